// Round 1
// baseline (663.799 us; speedup 1.0000x reference)
//
#include <hip/hip_runtime.h>
#include <cstdint>

#define FP8_MAX 448.0f
#define EPSF 1.1920928955078125e-07f

typedef float floatx4 __attribute__((ext_vector_type(4)));

// sizes
#define BATCH 8
#define MDIM 2048
#define KDIM 2048
#define NDIM 2048
#define NELEM ((long)BATCH * MDIM * KDIM)   // 33554432 per tensor
#define N4 (NELEM / 4)

// ws layout: [0..7]: amax_x, amax_w (uint bits). [256 ..): qx bytes, then qwT bytes.
#define QX_OFF 256
#define QW_OFF (256 + NELEM)

static __device__ __forceinline__ float wave_max(float v) {
    #pragma unroll
    for (int off = 32; off > 0; off >>= 1)
        v = fmaxf(v, __shfl_xor(v, off, 64));
    return v;
}

__global__ void amax_kernel(const float4* __restrict__ x, const float4* __restrict__ w,
                            unsigned int* __restrict__ amax) {
    const float4* p = blockIdx.y ? w : x;
    unsigned int* outp = amax + blockIdx.y;
    long idx = (long)blockIdx.x * blockDim.x + threadIdx.x;
    long stride = (long)gridDim.x * blockDim.x;
    float m = 0.f;
    for (long i = idx; i < N4; i += stride) {
        float4 v = p[i];
        m = fmaxf(m, fmaxf(fmaxf(fabsf(v.x), fabsf(v.y)), fmaxf(fabsf(v.z), fabsf(v.w))));
    }
    m = wave_max(m);
    __shared__ float smax[4];
    int lane = threadIdx.x & 63, wv = threadIdx.x >> 6;
    if (lane == 0) smax[wv] = m;
    __syncthreads();
    if (threadIdx.x == 0) {
        m = fmaxf(fmaxf(smax[0], smax[1]), fmaxf(smax[2], smax[3]));
        atomicMax(outp, __float_as_uint(m));  // all values >= 0: uint order == float order
    }
}

static __device__ __forceinline__ uint32_t quant4(float4 v, float s) {
    float a = fminf(fmaxf(v.x * s, -FP8_MAX), FP8_MAX);
    float b = fminf(fmaxf(v.y * s, -FP8_MAX), FP8_MAX);
    float c = fminf(fmaxf(v.z * s, -FP8_MAX), FP8_MAX);
    float d = fminf(fmaxf(v.w * s, -FP8_MAX), FP8_MAX);
    uint32_t r = (uint32_t)__builtin_amdgcn_cvt_pk_fp8_f32(a, b, 0, false);
    r = (uint32_t)__builtin_amdgcn_cvt_pk_fp8_f32(c, d, (int)r, true);
    return r;  // bytes [x,y,z,w] little-endian
}

__global__ void quant_x_kernel(const float4* __restrict__ x, uint32_t* __restrict__ qx,
                               const unsigned int* __restrict__ amax) {
    float ax = fmaxf(__uint_as_float(amax[0]), EPSF);
    float s = FP8_MAX / ax;
    long idx = (long)blockIdx.x * blockDim.x + threadIdx.x;
    long stride = (long)gridDim.x * blockDim.x;
    for (long i = idx; i < N4; i += stride)
        qx[i] = quant4(x[i], s);
}

// quantize + transpose W: global [b][k][n] (n contiguous) -> qwT [b][n][k] (k contiguous)
// tile 64(k) x 64(n), LDS byte-transpose with padded stride 68.
__global__ void quant_w_kernel(const float* __restrict__ w, uint8_t* __restrict__ qwT,
                               const unsigned int* __restrict__ amax) {
    float aw = fmaxf(__uint_as_float(amax[1]), EPSF);
    float s = FP8_MAX / aw;
    __shared__ uint8_t ldsT[64 * 68];
    int t = threadIdx.x;
    int n0 = blockIdx.x * 64, k0 = blockIdx.y * 64;
    long base = (long)blockIdx.z * KDIM * NDIM;
    int nl = (t & 15) * 4;
    int kl = t >> 4;  // 0..15
    #pragma unroll
    for (int it = 0; it < 4; ++it) {
        int k = kl + it * 16;
        float4 v = *(const float4*)(w + base + (long)(k0 + k) * NDIM + n0 + nl);
        uint32_t r = quant4(v, s);
        ldsT[(nl + 0) * 68 + k] = (uint8_t)(r);
        ldsT[(nl + 1) * 68 + k] = (uint8_t)(r >> 8);
        ldsT[(nl + 2) * 68 + k] = (uint8_t)(r >> 16);
        ldsT[(nl + 3) * 68 + k] = (uint8_t)(r >> 24);
    }
    __syncthreads();
    int n = t >> 2, c = t & 3;
    const uint8_t* src = &ldsT[n * 68 + c * 16];
    uint4 d;
    d.x = *(const uint32_t*)(src + 0);
    d.y = *(const uint32_t*)(src + 4);
    d.z = *(const uint32_t*)(src + 8);
    d.w = *(const uint32_t*)(src + 12);
    *(uint4*)(qwT + base + (long)(n0 + n) * KDIM + k0 + c * 16) = d;
}

// GEMM: C[b][m][n] = (qx[b] . qwT[b]^T) * ds + bias[b][n]
// 128x128 tile, BK=64, 256 threads = 4 waves (2x2), 4x4 16x16x32 fp8 MFMA per wave.
#define BM 128
#define BN 128
#define BK 64

__global__ __launch_bounds__(256) void gemm_kernel(const uint8_t* __restrict__ qx,
                                                   const uint8_t* __restrict__ qwT,
                                                   const float* __restrict__ bias,
                                                   float* __restrict__ out,
                                                   const unsigned int* __restrict__ amax) {
    int b = blockIdx.z;
    int tm = blockIdx.y, tn = blockIdx.x;
    __shared__ uint8_t lA[BM * BK];  // 8 KB, row-major [m][k], lane-ordered for load_lds
    __shared__ uint8_t lB[BN * BK];  // 8 KB, row-major [n][k]
    int t = threadIdx.x, lane = t & 63, wv = t >> 6;
    int wm = wv & 1, wn = wv >> 1;

    const uint8_t* Ab = qx + (long)b * MDIM * KDIM + (long)tm * BM * KDIM;
    const uint8_t* Bb = qwT + (long)b * NDIM * KDIM + (long)tn * BN * KDIM;

    floatx4 acc[4][4] = {};

    // staging address pieces (2 rounds of 256 threads x 16B per tile)
    int lin0 = t, lin1 = 256 + t;
    int rowA0 = lin0 >> 2, chA0 = lin0 & 3;
    int rowA1 = lin1 >> 2, chA1 = lin1 & 3;

    for (int kt = 0; kt < KDIM / BK; ++kt) {
        long k0 = (long)kt * BK;
        __builtin_amdgcn_global_load_lds(
            (const __attribute__((address_space(1))) uint32_t*)(Ab + (long)rowA0 * KDIM + k0 + chA0 * 16),
            (__attribute__((address_space(3))) uint32_t*)(lA + lin0 * 16), 16, 0, 0);
        __builtin_amdgcn_global_load_lds(
            (const __attribute__((address_space(1))) uint32_t*)(Ab + (long)rowA1 * KDIM + k0 + chA1 * 16),
            (__attribute__((address_space(3))) uint32_t*)(lA + lin1 * 16), 16, 0, 0);
        __builtin_amdgcn_global_load_lds(
            (const __attribute__((address_space(1))) uint32_t*)(Bb + (long)rowA0 * KDIM + k0 + chA0 * 16),
            (__attribute__((address_space(3))) uint32_t*)(lB + lin0 * 16), 16, 0, 0);
        __builtin_amdgcn_global_load_lds(
            (const __attribute__((address_space(1))) uint32_t*)(Bb + (long)rowA1 * KDIM + k0 + chA1 * 16),
            (__attribute__((address_space(3))) uint32_t*)(lB + lin1 * 16), 16, 0, 0);
        __syncthreads();

        #pragma unroll
        for (int kk = 0; kk < 2; ++kk) {
            int koff = kk * 32 + (lane >> 4) * 8;
            long a_frag[4], b_frag[4];
            #pragma unroll
            for (int mt = 0; mt < 4; ++mt)
                a_frag[mt] = *(const long*)&lA[(wm * 64 + mt * 16 + (lane & 15)) * BK + koff];
            #pragma unroll
            for (int nt = 0; nt < 4; ++nt)
                b_frag[nt] = *(const long*)&lB[(wn * 64 + nt * 16 + (lane & 15)) * BK + koff];
            #pragma unroll
            for (int mt = 0; mt < 4; ++mt)
                #pragma unroll
                for (int nt = 0; nt < 4; ++nt)
                    acc[mt][nt] = __builtin_amdgcn_mfma_f32_16x16x32_fp8_fp8(
                        a_frag[mt], b_frag[nt], acc[mt][nt], 0, 0, 0);
        }
        __syncthreads();
    }

    float ax = fmaxf(__uint_as_float(amax[0]), EPSF);
    float aw = fmaxf(__uint_as_float(amax[1]), EPSF);
    float ds = (ax / FP8_MAX) * (aw / FP8_MAX);  // 1/(sx*sw)

    #pragma unroll
    for (int mt = 0; mt < 4; ++mt) {
        #pragma unroll
        for (int nt = 0; nt < 4; ++nt) {
            int col = tn * BN + wn * 64 + nt * 16 + (lane & 15);
            float bv = bias[(long)b * NDIM + col];
            int row0 = tm * BM + wm * 64 + mt * 16 + (lane >> 4) * 4;
            #pragma unroll
            for (int r = 0; r < 4; ++r) {
                out[((long)b * MDIM + row0 + r) * NDIM + col] = acc[mt][nt][r] * ds + bv;
            }
        }
    }
}

extern "C" void kernel_launch(void* const* d_in, const int* in_sizes, int n_in,
                              void* d_out, int out_size, void* d_ws, size_t ws_size,
                              hipStream_t stream) {
    const float* x = (const float*)d_in[0];
    const float* w = (const float*)d_in[1];
    const float* bias = (const float*)d_in[2];
    float* out = (float*)d_out;

    unsigned int* amax = (unsigned int*)d_ws;
    uint8_t* qx = (uint8_t*)d_ws + QX_OFF;
    uint8_t* qwT = (uint8_t*)d_ws + QW_OFF;
    (void)in_sizes; (void)n_in; (void)out_size; (void)ws_size;

    // zero the amax accumulators (ws is poisoned 0xAA before every launch)
    hipMemsetAsync(d_ws, 0, 8, stream);

    amax_kernel<<<dim3(1024, 2), 256, 0, stream>>>((const float4*)x, (const float4*)w, amax);
    quant_x_kernel<<<4096, 256, 0, stream>>>((const float4*)x, (uint32_t*)qx, amax);
    quant_w_kernel<<<dim3(NDIM / 64, KDIM / 64, BATCH), 256, 0, stream>>>(w, qwT, amax);
    gemm_kernel<<<dim3(NDIM / BN, MDIM / BM, BATCH), 256, 0, stream>>>(qx, qwT, bias, out, amax);
}

// Round 2
// 503.321 us; speedup vs baseline: 1.3188x; 1.3188x over previous
//
#include <hip/hip_runtime.h>
#include <cstdint>

#define FP8_MAX 448.0f
#define EPSF 1.1920928955078125e-07f

typedef float floatx4 __attribute__((ext_vector_type(4)));

// sizes
#define BATCH 8
#define MDIM 2048
#define KDIM 2048
#define NDIM 2048
#define NELEM ((long)BATCH * MDIM * KDIM)   // 33554432 per tensor
#define N4 (NELEM / 4)

// ws layout: [0..7]: amax_x, amax_w (uint bits). [256 ..): qx bytes, then qwT bytes.
#define QX_OFF 256
#define QW_OFF (256 + NELEM)

static __device__ __forceinline__ float wave_max(float v) {
    #pragma unroll
    for (int off = 32; off > 0; off >>= 1)
        v = fmaxf(v, __shfl_xor(v, off, 64));
    return v;
}

__global__ void amax_kernel(const float4* __restrict__ x, const float4* __restrict__ w,
                            unsigned int* __restrict__ amax) {
    const float4* p = blockIdx.y ? w : x;
    unsigned int* outp = amax + blockIdx.y;
    long idx = (long)blockIdx.x * blockDim.x + threadIdx.x;
    long stride = (long)gridDim.x * blockDim.x;
    float m = 0.f;
    for (long i = idx; i < N4; i += stride) {
        float4 v = p[i];
        m = fmaxf(m, fmaxf(fmaxf(fabsf(v.x), fabsf(v.y)), fmaxf(fabsf(v.z), fabsf(v.w))));
    }
    m = wave_max(m);
    __shared__ float smax[4];
    int lane = threadIdx.x & 63, wv = threadIdx.x >> 6;
    if (lane == 0) smax[wv] = m;
    __syncthreads();
    if (threadIdx.x == 0) {
        m = fmaxf(fmaxf(smax[0], smax[1]), fmaxf(smax[2], smax[3]));
        atomicMax(outp, __float_as_uint(m));  // all values >= 0: uint order == float order
    }
}

static __device__ __forceinline__ uint32_t quant4(float4 v, float s) {
    float a = fminf(fmaxf(v.x * s, -FP8_MAX), FP8_MAX);
    float b = fminf(fmaxf(v.y * s, -FP8_MAX), FP8_MAX);
    float c = fminf(fmaxf(v.z * s, -FP8_MAX), FP8_MAX);
    float d = fminf(fmaxf(v.w * s, -FP8_MAX), FP8_MAX);
    uint32_t r = (uint32_t)__builtin_amdgcn_cvt_pk_fp8_f32(a, b, 0, false);
    r = (uint32_t)__builtin_amdgcn_cvt_pk_fp8_f32(c, d, (int)r, true);
    return r;  // bytes [x,y,z,w] little-endian
}

__global__ void quant_x_kernel(const float4* __restrict__ x, uint32_t* __restrict__ qx,
                               const unsigned int* __restrict__ amax) {
    float ax = fmaxf(__uint_as_float(amax[0]), EPSF);
    float s = FP8_MAX / ax;
    long idx = (long)blockIdx.x * blockDim.x + threadIdx.x;
    long stride = (long)gridDim.x * blockDim.x;
    for (long i = idx; i < N4; i += stride)
        qx[i] = quant4(x[i], s);
}

// quantize + transpose W: global [b][k][n] (n contiguous) -> qwT [b][n][k] (k contiguous)
// tile 64(k) x 64(n), LDS byte-transpose with padded stride 68.
__global__ void quant_w_kernel(const float* __restrict__ w, uint8_t* __restrict__ qwT,
                               const unsigned int* __restrict__ amax) {
    float aw = fmaxf(__uint_as_float(amax[1]), EPSF);
    float s = FP8_MAX / aw;
    __shared__ uint8_t ldsT[64 * 68];
    int t = threadIdx.x;
    int n0 = blockIdx.x * 64, k0 = blockIdx.y * 64;
    long base = (long)blockIdx.z * KDIM * NDIM;
    int nl = (t & 15) * 4;
    int kl = t >> 4;  // 0..15
    #pragma unroll
    for (int it = 0; it < 4; ++it) {
        int k = kl + it * 16;
        float4 v = *(const float4*)(w + base + (long)(k0 + k) * NDIM + n0 + nl);
        uint32_t r = quant4(v, s);
        ldsT[(nl + 0) * 68 + k] = (uint8_t)(r);
        ldsT[(nl + 1) * 68 + k] = (uint8_t)(r >> 8);
        ldsT[(nl + 2) * 68 + k] = (uint8_t)(r >> 16);
        ldsT[(nl + 3) * 68 + k] = (uint8_t)(r >> 24);
    }
    __syncthreads();
    int n = t >> 2, c = t & 3;
    const uint8_t* src = &ldsT[n * 68 + c * 16];
    uint4 d;
    d.x = *(const uint32_t*)(src + 0);
    d.y = *(const uint32_t*)(src + 4);
    d.z = *(const uint32_t*)(src + 8);
    d.w = *(const uint32_t*)(src + 12);
    *(uint4*)(qwT + base + (long)(n0 + n) * KDIM + k0 + c * 16) = d;
}

// GEMM: C[b][m][n] = (qx[b] . qwT[b]^T) * ds + bias[b][n]
// 128x128 tile, BK=64 bytes, 256 threads = 4 waves (2x2), 4x4 16x16x32 fp8 MFMA per wave.
// LDS layout XOR-swizzled at 16B-chunk granularity: physical chunk = global chunk ^ ((row>>1)&3).
// Swizzle applied on the GLOBAL source address at staging (LDS dest must stay lane-ordered
// for global_load_lds), and on the LDS address at fragment-read time. This gives 8 distinct
// start banks per 16-lane phase (2-way aliasing = free) instead of 4 (8-way serialize),
// which was 1.17e8 conflict cycles = 60% of round-1 gemm time.
#define BM 128
#define BN 128
#define BK 64

__global__ __launch_bounds__(256) void gemm_kernel(const uint8_t* __restrict__ qx,
                                                   const uint8_t* __restrict__ qwT,
                                                   const float* __restrict__ bias,
                                                   float* __restrict__ out,
                                                   const unsigned int* __restrict__ amax) {
    int b = blockIdx.z;
    int tm = blockIdx.y, tn = blockIdx.x;
    __shared__ uint8_t lA[BM * BK];  // 8 KB
    __shared__ uint8_t lB[BN * BK];  // 8 KB
    int t = threadIdx.x, lane = t & 63, wv = t >> 6;
    int wm = wv & 1, wn = wv >> 1;
    int m = lane & 15, g = lane >> 4;
    int ghi = g >> 1, glo8 = (g & 1) * 8;

    const uint8_t* Ab = qx + (long)b * MDIM * KDIM + (long)tm * BM * KDIM;
    const uint8_t* Bb = qwT + (long)b * NDIM * KDIM + (long)tn * BN * KDIM;

    floatx4 acc[4][4] = {};

    // staging: 2 rounds of 256 threads x 16B per tile; source chunk XOR-swizzled
    int lin0 = t, lin1 = 256 + t;
    int row0 = lin0 >> 2, row1 = lin1 >> 2;
    int src0 = ((lin0 & 3) ^ ((row0 >> 1) & 3)) * 16;
    int src1 = ((lin1 & 3) ^ ((row1 >> 1) & 3)) * 16;

    for (int kt = 0; kt < KDIM / BK; ++kt) {
        long k0 = (long)kt * BK;
        __builtin_amdgcn_global_load_lds(
            (const __attribute__((address_space(1))) uint32_t*)(Ab + (long)row0 * KDIM + k0 + src0),
            (__attribute__((address_space(3))) uint32_t*)(lA + lin0 * 16), 16, 0, 0);
        __builtin_amdgcn_global_load_lds(
            (const __attribute__((address_space(1))) uint32_t*)(Ab + (long)row1 * KDIM + k0 + src1),
            (__attribute__((address_space(3))) uint32_t*)(lA + lin1 * 16), 16, 0, 0);
        __builtin_amdgcn_global_load_lds(
            (const __attribute__((address_space(1))) uint32_t*)(Bb + (long)row0 * KDIM + k0 + src0),
            (__attribute__((address_space(3))) uint32_t*)(lB + lin0 * 16), 16, 0, 0);
        __builtin_amdgcn_global_load_lds(
            (const __attribute__((address_space(1))) uint32_t*)(Bb + (long)row1 * KDIM + k0 + src1),
            (__attribute__((address_space(3))) uint32_t*)(lB + lin1 * 16), 16, 0, 0);
        __syncthreads();

        #pragma unroll
        for (int kk = 0; kk < 2; ++kk) {
            int gc = kk * 2 + ghi;  // global 16B-chunk index within the row
            long a_frag[4], b_frag[4];
            #pragma unroll
            for (int mt = 0; mt < 4; ++mt) {
                int r = wm * 64 + mt * 16 + m;
                int pc = gc ^ ((r >> 1) & 3);
                a_frag[mt] = *(const long*)&lA[r * BK + pc * 16 + glo8];
            }
            #pragma unroll
            for (int nt = 0; nt < 4; ++nt) {
                int r = wn * 64 + nt * 16 + m;
                int pc = gc ^ ((r >> 1) & 3);
                b_frag[nt] = *(const long*)&lB[r * BK + pc * 16 + glo8];
            }
            #pragma unroll
            for (int mt = 0; mt < 4; ++mt)
                #pragma unroll
                for (int nt = 0; nt < 4; ++nt)
                    acc[mt][nt] = __builtin_amdgcn_mfma_f32_16x16x32_fp8_fp8(
                        a_frag[mt], b_frag[nt], acc[mt][nt], 0, 0, 0);
        }
        __syncthreads();
    }

    float ax = fmaxf(__uint_as_float(amax[0]), EPSF);
    float aw = fmaxf(__uint_as_float(amax[1]), EPSF);
    float ds = (ax / FP8_MAX) * (aw / FP8_MAX);  // 1/(sx*sw)

    #pragma unroll
    for (int mt = 0; mt < 4; ++mt) {
        #pragma unroll
        for (int nt = 0; nt < 4; ++nt) {
            int col = tn * BN + wn * 64 + nt * 16 + m;
            float bv = bias[(long)b * NDIM + col];
            int row0e = tm * BM + wm * 64 + mt * 16 + g * 4;
            #pragma unroll
            for (int r = 0; r < 4; ++r) {
                out[((long)b * MDIM + row0e + r) * NDIM + col] = acc[mt][nt][r] * ds + bv;
            }
        }
    }
}

extern "C" void kernel_launch(void* const* d_in, const int* in_sizes, int n_in,
                              void* d_out, int out_size, void* d_ws, size_t ws_size,
                              hipStream_t stream) {
    const float* x = (const float*)d_in[0];
    const float* w = (const float*)d_in[1];
    const float* bias = (const float*)d_in[2];
    float* out = (float*)d_out;

    unsigned int* amax = (unsigned int*)d_ws;
    uint8_t* qx = (uint8_t*)d_ws + QX_OFF;
    uint8_t* qwT = (uint8_t*)d_ws + QW_OFF;
    (void)in_sizes; (void)n_in; (void)out_size; (void)ws_size;

    // zero the amax accumulators (ws is poisoned 0xAA before every launch)
    hipMemsetAsync(d_ws, 0, 8, stream);

    amax_kernel<<<dim3(2048, 2), 256, 0, stream>>>((const float4*)x, (const float4*)w, amax);
    quant_x_kernel<<<8192, 256, 0, stream>>>((const float4*)x, (uint32_t*)qx, amax);
    quant_w_kernel<<<dim3(NDIM / 64, KDIM / 64, BATCH), 256, 0, stream>>>(w, qwT, amax);
    gemm_kernel<<<dim3(NDIM / BN, MDIM / BM, BATCH), 256, 0, stream>>>(qx, qwT, bias, out, amax);
}